// Round 12
// baseline (26.432 us; speedup 1.0000x reference)
//
#include <hip/hip_runtime.h>

#define HWX 65536
#define NQ 128      // N (queries)
#define KT 64       // K (targets)
#define CC 134      // classes
#define BB 2        // batch
#define NW 128      // k-windows
#define WIN 512     // floats per window
#define SUB 64      // floats per A sub-tile
#define NSUB 8      // sub-tiles per window
#define EPSI 1e-5f

typedef __attribute__((ext_vector_type(4))) float f32x4;
typedef __attribute__((ext_vector_type(8))) short bf16x8;
typedef __attribute__((ext_vector_type(2))) unsigned int u32x2;

union FU { unsigned int u[4]; bf16x8 v; };

static __device__ __forceinline__ unsigned int cvtpk(float lo, float hi) {
  unsigned int r;
  asm("v_cvt_pk_bf16_f32 %0, %1, %2" : "=v"(r) : "v"(lo), "v"(hi));
  return r;
}

// async global->LDS, 16B/lane; LDS dest = wave-uniform base + lane*16 (linear).
// Swizzle is folded into the per-lane GLOBAL source address (G21 pattern).
static __device__ __forceinline__ void gload16(const float* g, float* l) {
  __builtin_amdgcn_global_load_lds(
      (const __attribute__((address_space(1))) void*)g,
      (__attribute__((address_space(3))) void*)l, 16, 0, 0);
}

// ---------------- int64-vs-int32 detection (atomic-fallback path only) ------
__global__ void hm_detect(const unsigned int* __restrict__ t,
                          unsigned int* __restrict__ flag) {
  unsigned int w = t[threadIdx.x * 2 + 1];
  unsigned long long any = __ballot(w != 0u);
  if (threadIdx.x == 0) *flag = (any != 0ull) ? 1u : 0u;  // 1 => int32 data
}

// ---------------- stage 1: barrier-free wave-private pipeline ---------------
// grid = BB*NW = 256 blocks (1/CU, 128 KB LDS), 512 threads (8 waves).
// Phase 1 (once): stage B window (64x512) as swizzled bf16 into shared LDS;
//   exact fp32 B-rowsums during conversion; ONE vmcnt(0)+__syncthreads().
// Phase 2 (main loop, NO barriers): each wave owns A rows [wv*16,+16) with a
//   wave-private double-buffered 16x64 fp32 LDS tile filled by global_load_lds.
//   Loop: ISSUE_A(t+1) -> COMP(t) -> s_waitcnt vmcnt(0) (per-wave) -> swap.
//   (R10-proven schedule. The vmcnt(4) counted-wait variant raced (R11) and
//   is abandoned: per-wave vmcnt accounting is not robust under this
//   compiler's scheduling. Do not reintroduce without disasm evidence.)
template <bool ATOMIC>
__global__ __launch_bounds__(512)
void hm_stage1(const float* __restrict__ in_mask, const float* __restrict__ tg_mask,
               void* __restrict__ Iout, float* __restrict__ RSin,
               float* __restrict__ RStg) {
  const int w = blockIdx.x & (NW - 1);
  const int b = blockIdx.x >> 7;
  const int tid = threadIdx.x;
  const int lane = tid & 63;
  const int wv = tid >> 6;            // wave 0..7
  const int l16 = lane & 15;
  const int lg = lane >> 4;

  __shared__ __align__(16) unsigned short lB[64 * 512];   // 64 KB bf16, swizzled
  __shared__ __align__(16) float lA[8][2][16 * SUB];      // 4 KB x2 per wave

  const float* Ab = in_mask + (size_t)b * NQ * HWX + (size_t)w * WIN;
  const float* Bb = tg_mask + (size_t)b * KT * HWX + (size_t)w * WIN;

  f32x4 acc[4];
  #pragma unroll
  for (int i = 0; i < 4; ++i) acc[i] = f32x4{0.f, 0.f, 0.f, 0.f};
  float rsA = 0.f;

  // ---- wave-private A tile staging (rows wv*16 + [0,16), 64 floats K) ------
  auto ISSUE_A = [&](int t, int buf) {
    float* dst = &lA[wv][buf][0];
    #pragma unroll
    for (int q = 0; q < 4; ++q) {
      const int row = q * 4 + (lane >> 4);           // 0..15 (wave-local)
      const int csrc = (lane & 15) ^ (row & 7);      // source-side XOR swizzle
      gload16(Ab + (size_t)(wv * 16 + row) * HWX + t * SUB + csrc * 4,
              dst + q * 256);                        // 4 rows x 256 B linear
    }
  };

  // ---- phase 1: prefetch A(0), then stage B window as bf16 -----------------
  ISSUE_A(0, 0);
  {
    const int brow = tid >> 3;          // 0..63
    const int bl = tid & 7;             // 8 threads per row
    float rsB = 0.f;
    char* B8 = (char*)lB;
    #pragma unroll
    for (int j = 0; j < 16; ++j) {
      const int c = bl + j * 8;         // 16B fp32 chunk index 0..127
      f32x4 x = *(const f32x4*)(Bb + (size_t)brow * HWX + c * 4);
      rsB += (x.x + x.y) + (x.z + x.w);
      u32x2 v;
      v.x = cvtpk(x.x, x.y); v.y = cvtpk(x.z, x.w);
      const int ch16 = c >> 1, half = c & 1;        // bf16 16B-chunk 0..63
      *(u32x2*)(B8 + (size_t)brow * 1024 +
                (((ch16 ^ (brow & 7)) << 4) + half * 8)) = v;
    }
    rsB += __shfl_xor(rsB, 1); rsB += __shfl_xor(rsB, 2); rsB += __shfl_xor(rsB, 4);
    if (bl == 0) {
      if (!ATOMIC) RStg[(size_t)(b * NW + w) * KT + brow] = rsB;
      else         atomicAdd(&RStg[b * KT + brow], rsB);
    }
  }
  asm volatile("s_waitcnt vmcnt(0)" ::: "memory");  // A(0)+B loads complete
  __syncthreads();                                   // B visible to all waves

  // ---- COMP: one A sub-tile vs all 64 B cols (8 MFMA), fp32->bf16 on read --
  auto COMP = [&](int t, int buf) {
    const float* A32 = &lA[wv][buf][0];
    const char* B8 = (const char*)lB;
    const int x7 = l16 & 7;
    #pragma unroll
    for (int s = 0; s < 2; ++s) {
      const int g0 = s * 8 + lg * 2;                 // A 16B-chunk index
      f32x4 alo = *(const f32x4*)(A32 + l16 * SUB + ((g0 ^ x7) << 2));
      f32x4 ahi = *(const f32x4*)(A32 + l16 * SUB + (((g0 + 1) ^ x7) << 2));
      rsA += (alo.x + alo.y) + (alo.z + alo.w) + (ahi.x + ahi.y) + (ahi.z + ahi.w);
      FU fa;
      fa.u[0] = cvtpk(alo.x, alo.y); fa.u[1] = cvtpk(alo.z, alo.w);
      fa.u[2] = cvtpk(ahi.x, ahi.y); fa.u[3] = cvtpk(ahi.z, ahi.w);
      const int c16 = t * 8 + s * 4 + lg;            // B 16B-chunk in window
      #pragma unroll
      for (int cf = 0; cf < 4; ++cf) {
        const int Rb = cf * 16 + l16;
        bf16x8 fbv = *(const bf16x8*)(B8 + (size_t)Rb * 1024 +
                                      ((c16 ^ (Rb & 7)) << 4));
        acc[cf] = __builtin_amdgcn_mfma_f32_16x16x32_bf16(fa.v, fbv, acc[cf], 0, 0, 0);
      }
    }
  };

  // ---- phase 2: barrier-free per-wave pipeline (R10-proven schedule) -------
  #pragma unroll
  for (int t = 0; t < NSUB; ++t) {
    const int buf = t & 1;
    if (t + 1 < NSUB) ISSUE_A(t + 1, buf ^ 1);
    COMP(t, buf);
    asm volatile("s_waitcnt vmcnt(0)" ::: "memory"); // own A loads complete
    __builtin_amdgcn_sched_barrier(0);               // pin: nothing hoists above
  }

  // ---- write partials (C layout: col = cf*16+l16, row = wv*16+lg*4+j) ------
  if (!ATOMIC) {
    // bf16-packed: u32 slot s in [0,32) holds cols (s, s+32) as (lo16, hi16)
    unsigned int* P = (unsigned int*)Iout;
    #pragma unroll
    for (int j = 0; j < 4; ++j) {
      const int row = wv * 16 + lg * 4 + j;
      const size_t base = ((size_t)(b * NW + w) * NQ + row) * 32;
      P[base + l16]      = cvtpk(acc[0][j], acc[2][j]);
      P[base + l16 + 16] = cvtpk(acc[1][j], acc[3][j]);
    }
  } else {
    float* Iacc = (float*)Iout;
    #pragma unroll
    for (int cf = 0; cf < 4; ++cf)
      #pragma unroll
      for (int j = 0; j < 4; ++j) {
        const int row = wv * 16 + lg * 4 + j;
        atomicAdd(&Iacc[((size_t)b * NQ + row) * KT + cf * 16 + l16], acc[cf][j]);
      }
  }

  // ---- A rowsums: reduce the 4 lanes (lg) sharing each row -----------------
  rsA += __shfl_xor(rsA, 16); rsA += __shfl_xor(rsA, 32);
  if (lg == 0) {
    const int row = wv * 16 + l16;
    if (!ATOMIC) RSin[(size_t)(b * NW + w) * NQ + row] = rsA;
    else         atomicAdd(&RSin[b * NQ + row], rsA);
  }
}

// ---------------- stage 2 (partial mode): reduce + dice + class gather ------
__global__ __launch_bounds__(256)
void hm_stage2(const float* __restrict__ cprob, const void* __restrict__ tcls,
               const unsigned int* __restrict__ P, const float* __restrict__ RSin,
               const float* __restrict__ RStg, float* __restrict__ out) {
  const int bn = blockIdx.x;            // b*NQ + n
  const int b = bn >> 7, n = bn & 127;
  const int k = threadIdx.x & 63;
  const int wq = threadIdx.x >> 6;      // 0..3
  const int slot = k & 31;
  const bool hi = k >= 32;
  float I = 0.f, ra = 0.f, rg = 0.f;
  #pragma unroll 8
  for (int ww = 0; ww < NW / 4; ++ww) {
    const int w = wq * (NW / 4) + ww;
    const unsigned int v = P[((size_t)(b * NW + w) * NQ + n) * 32 + slot];
    const unsigned int bits = hi ? (v & 0xffff0000u) : (v << 16);
    I  += __uint_as_float(bits);
    ra += RSin[(size_t)(b * NW + w) * NQ + n];
    rg += RStg[(size_t)(b * NW + w) * KT + k];
  }
  __shared__ float sI[4][64];
  __shared__ float sG[4][64];
  __shared__ float sR[4];
  sI[wq][k] = I;
  sG[wq][k] = rg;
  if (k == 0) sR[wq] = ra;
  __syncthreads();
  if (wq == 0) {
    I  = sI[0][k] + sI[1][k] + sI[2][k] + sI[3][k];
    rg = sG[0][k] + sG[1][k] + sG[2][k] + sG[3][k];
    ra = sR[0] + sR[1] + sR[2] + sR[3];
    const unsigned int hiw = ((const unsigned int*)tcls)[k * 2 + 1];
    const bool i32 = (__ballot(hiw != 0u) != 0ull);
    int tc = i32 ? ((const int*)tcls)[b * KT + k]
                 : (int)((const long long*)tcls)[b * KT + k];
    const float c = cprob[((size_t)b * NQ + n) * CC + tc];
    out[(size_t)bn * KT + k] = c * (2.f * I + EPSI) / (ra + rg + EPSI);
  }
}

// ---------------- stage 2 (atomic fallback mode) ----------------------------
__global__ __launch_bounds__(256)
void hm_stage2_direct(const float* __restrict__ cprob, const void* __restrict__ tcls,
                      const unsigned int* __restrict__ flag,
                      const float* __restrict__ Iacc, const float* __restrict__ RSin,
                      const float* __restrict__ RStg, float* __restrict__ out) {
  const int idx = blockIdx.x * 256 + threadIdx.x;
  const int k = idx & 63;
  const int n = (idx >> 6) & 127;
  const int b = idx >> 13;
  const float I  = Iacc[idx];
  const float ra = RSin[b * NQ + n];
  const float rg = RStg[b * KT + k];
  int tc;
  if (*flag) tc = ((const int*)tcls)[b * KT + k];
  else       tc = (int)((const long long*)tcls)[b * KT + k];
  const float c = cprob[((size_t)b * NQ + n) * CC + tc];
  out[idx] = c * (2.f * I + EPSI) / (ra + rg + EPSI);
}

__global__ void hm_zero(float* __restrict__ p, int n) {
  int i = blockIdx.x * blockDim.x + threadIdx.x;
  if (i < n) p[i] = 0.f;
}

extern "C" void kernel_launch(void* const* d_in, const int* in_sizes, int n_in,
                              void* d_out, int out_size, void* d_ws, size_t ws_size,
                              hipStream_t stream) {
  const float* cprob = (const float*)d_in[0];   // (2,128,134) f32
  const float* imask = (const float*)d_in[1];   // (2,128,65536) f32
  const float* tmask = (const float*)d_in[2];   // (2,64,65536) f32
  const void*  tcls  = d_in[3];                 // (2,64) int64 (or int32)
  float* out = (float*)d_out;                   // (2,128,64) f32

  const size_t p_u32  = (size_t)BB * NW * NQ * 32;   // 1 Mi u32 (4 MB, bf16 pairs)
  const size_t rsin_f = (size_t)BB * NW * NQ;        // 32,768
  const size_t rstg_f = (size_t)BB * NW * KT;        // 16,384
  const size_t need   = (p_u32 + rsin_f + rstg_f) * 4;

  char* ws = (char*)d_ws;
  if (ws_size >= need) {
    unsigned int* P = (unsigned int*)ws;
    float* RSin = (float*)(P + p_u32);
    float* RStg = RSin + rsin_f;
    hm_stage1<false><<<BB * NW, 512, 0, stream>>>(imask, tmask, P, RSin, RStg);
    hm_stage2<<<BB * NQ, 256, 0, stream>>>(cprob, tcls, P, RSin, RStg, out);
  } else {
    // small-scratch atomic fallback (~67 KB)
    float* Iacc = (float*)ws;                     // 16384 floats
    float* RSin = Iacc + (size_t)BB * NQ * KT;    // 256
    float* RStg = RSin + BB * NQ;                 // 128
    unsigned int* flag = (unsigned int*)(RStg + BB * KT);
    const int zn = BB * NQ * KT + BB * NQ + BB * KT;
    hm_zero<<<(zn + 255) / 256, 256, 0, stream>>>(Iacc, zn);
    hm_detect<<<1, 64, 0, stream>>>((const unsigned int*)tcls, flag);
    hm_stage1<true><<<BB * NW, 512, 0, stream>>>(imask, tmask, Iacc, RSin, RStg);
    hm_stage2_direct<<<(BB * NQ * KT) / 256, 256, 0, stream>>>(cprob, tcls, flag, Iacc, RSin, RStg, out);
  }
}

// Round 13
// 26.163 us; speedup vs baseline: 1.0103x; 1.0103x over previous
//
#include <hip/hip_runtime.h>

#define HWX 65536
#define NQ 128      // N (queries)
#define KT 64       // K (targets)
#define CC 134      // classes
#define BB 2        // batch
#define NW 128      // k-windows
#define WIN 512     // floats per window
#define SUB 64      // floats per A sub-tile
#define NSUB 8      // sub-tiles per window
#define EPSI 1e-5f

typedef __attribute__((ext_vector_type(4))) float f32x4;
typedef __attribute__((ext_vector_type(8))) short bf16x8;
typedef __attribute__((ext_vector_type(2))) unsigned int u32x2;

union FU { unsigned int u[4]; bf16x8 v; };

static __device__ __forceinline__ unsigned int cvtpk(float lo, float hi) {
  unsigned int r;
  asm("v_cvt_pk_bf16_f32 %0, %1, %2" : "=v"(r) : "v"(lo), "v"(hi));
  return r;
}

// async global->LDS, 16B/lane; LDS dest = wave-uniform base + lane*16 (linear).
// Swizzle is folded into the per-lane GLOBAL source address (G21 pattern).
static __device__ __forceinline__ void gload16(const float* g, float* l) {
  __builtin_amdgcn_global_load_lds(
      (const __attribute__((address_space(1))) void*)g,
      (__attribute__((address_space(3))) void*)l, 16, 0, 0);
}

// ---------------- int64-vs-int32 detection (atomic-fallback path only) ------
__global__ void hm_detect(const unsigned int* __restrict__ t,
                          unsigned int* __restrict__ flag) {
  unsigned int w = t[threadIdx.x * 2 + 1];
  unsigned long long any = __ballot(w != 0u);
  if (threadIdx.x == 0) *flag = (any != 0ull) ? 1u : 0u;  // 1 => int32 data
}

// ---------------- stage 1: barrier-free wave-private pipeline ---------------
// grid = BB*NW = 256 blocks (1/CU, 128 KB LDS), 512 threads (8 waves).
// Phase 1 (once): stage B window (64x512) as swizzled bf16 into shared LDS;
//   exact fp32 B-rowsums during conversion; ONE vmcnt(0)+__syncthreads().
// Phase 2 (main loop, NO cross-wave barriers): each wave owns A rows
//   [wv*16,+16), double-buffered 16x64 fp32 wave-private LDS tile via
//   global_load_lds. Counted-wait schedule:
//     ISSUE_A(t+1) -> vmcnt(4) [tile t done, t+1 flying] -> SBAR -> COMP(t)
//     -> SBAR (trailing).
//   The TRAILING sched_barrier(0) is load-bearing: without it the compiler
//   may hoist ISSUE(t+2)'s gloads above COMP(t)'s ds_reads of the SAME
//   buffer (global_load_lds's LDS-write operand is invisible to alias
//   analysis) -- that was R11's race. With it, ISSUE(t+2) issues only after
//   COMP(t)'s reads are consumed (lgkmcnt-fenced by its MFMAs), and the DMA
//   write physically lands >=HBM-latency later. vmcnt counting is exact:
//   4 gloads per ISSUE, no other VMEM ops inside the loop.
template <bool ATOMIC>
__global__ __launch_bounds__(512)
void hm_stage1(const float* __restrict__ in_mask, const float* __restrict__ tg_mask,
               void* __restrict__ Iout, float* __restrict__ RSin,
               float* __restrict__ RStg) {
  const int w = blockIdx.x & (NW - 1);
  const int b = blockIdx.x >> 7;
  const int tid = threadIdx.x;
  const int lane = tid & 63;
  const int wv = tid >> 6;            // wave 0..7
  const int l16 = lane & 15;
  const int lg = lane >> 4;

  __shared__ __align__(16) unsigned short lB[64 * 512];   // 64 KB bf16, swizzled
  __shared__ __align__(16) float lA[8][2][16 * SUB];      // 4 KB x2 per wave

  const float* Ab = in_mask + (size_t)b * NQ * HWX + (size_t)w * WIN;
  const float* Bb = tg_mask + (size_t)b * KT * HWX + (size_t)w * WIN;

  f32x4 acc[4];
  #pragma unroll
  for (int i = 0; i < 4; ++i) acc[i] = f32x4{0.f, 0.f, 0.f, 0.f};
  float rsA = 0.f;

  // ---- wave-private A tile staging (rows wv*16 + [0,16), 64 floats K) ------
  auto ISSUE_A = [&](int t, int buf) {
    float* dst = &lA[wv][buf][0];
    #pragma unroll
    for (int q = 0; q < 4; ++q) {
      const int row = q * 4 + (lane >> 4);           // 0..15 (wave-local)
      const int csrc = (lane & 15) ^ (row & 7);      // source-side XOR swizzle
      gload16(Ab + (size_t)(wv * 16 + row) * HWX + t * SUB + csrc * 4,
              dst + q * 256);                        // 4 rows x 256 B linear
    }
  };

  // ---- phase 1: prefetch A(0), then stage B window as bf16 -----------------
  ISSUE_A(0, 0);
  {
    const int brow = tid >> 3;          // 0..63
    const int bl = tid & 7;             // 8 threads per row
    float rsB = 0.f;
    char* B8 = (char*)lB;
    #pragma unroll
    for (int j = 0; j < 16; ++j) {
      const int c = bl + j * 8;         // 16B fp32 chunk index 0..127
      f32x4 x = *(const f32x4*)(Bb + (size_t)brow * HWX + c * 4);
      rsB += (x.x + x.y) + (x.z + x.w);
      u32x2 v;
      v.x = cvtpk(x.x, x.y); v.y = cvtpk(x.z, x.w);
      const int ch16 = c >> 1, half = c & 1;        // bf16 16B-chunk 0..63
      *(u32x2*)(B8 + (size_t)brow * 1024 +
                (((ch16 ^ (brow & 7)) << 4) + half * 8)) = v;
    }
    rsB += __shfl_xor(rsB, 1); rsB += __shfl_xor(rsB, 2); rsB += __shfl_xor(rsB, 4);
    if (bl == 0) {
      if (!ATOMIC) RStg[(size_t)(b * NW + w) * KT + brow] = rsB;
      else         atomicAdd(&RStg[b * KT + brow], rsB);
    }
  }
  asm volatile("s_waitcnt vmcnt(0)" ::: "memory");  // A(0)+B loads complete
  __syncthreads();                                   // B visible to all waves

  // ---- COMP: one A sub-tile vs all 64 B cols (8 MFMA), fp32->bf16 on read --
  auto COMP = [&](int t, int buf) {
    const float* A32 = &lA[wv][buf][0];
    const char* B8 = (const char*)lB;
    const int x7 = l16 & 7;
    #pragma unroll
    for (int s = 0; s < 2; ++s) {
      const int g0 = s * 8 + lg * 2;                 // A 16B-chunk index
      f32x4 alo = *(const f32x4*)(A32 + l16 * SUB + ((g0 ^ x7) << 2));
      f32x4 ahi = *(const f32x4*)(A32 + l16 * SUB + (((g0 + 1) ^ x7) << 2));
      rsA += (alo.x + alo.y) + (alo.z + alo.w) + (ahi.x + ahi.y) + (ahi.z + ahi.w);
      FU fa;
      fa.u[0] = cvtpk(alo.x, alo.y); fa.u[1] = cvtpk(alo.z, alo.w);
      fa.u[2] = cvtpk(ahi.x, ahi.y); fa.u[3] = cvtpk(ahi.z, ahi.w);
      const int c16 = t * 8 + s * 4 + lg;            // B 16B-chunk in window
      #pragma unroll
      for (int cf = 0; cf < 4; ++cf) {
        const int Rb = cf * 16 + l16;
        bf16x8 fbv = *(const bf16x8*)(B8 + (size_t)Rb * 1024 +
                                      ((c16 ^ (Rb & 7)) << 4));
        acc[cf] = __builtin_amdgcn_mfma_f32_16x16x32_bf16(fa.v, fbv, acc[cf], 0, 0, 0);
      }
    }
  };

  // ---- phase 2: barrier-free per-wave pipeline, counted waits + fences -----
  #pragma unroll
  for (int t = 0; t < NSUB; ++t) {
    const int buf = t & 1;
    if (t + 1 < NSUB) {
      ISSUE_A(t + 1, buf ^ 1);
      asm volatile("s_waitcnt vmcnt(4)" ::: "memory");  // tile t done, t+1 flying
    } else {
      asm volatile("s_waitcnt vmcnt(0)" ::: "memory");  // last tile done
    }
    __builtin_amdgcn_sched_barrier(0);   // no hoist above the wait
    COMP(t, buf);
    __builtin_amdgcn_sched_barrier(0);   // next ISSUE cannot hoist above COMP
  }

  // ---- write partials (C layout: col = cf*16+l16, row = wv*16+lg*4+j) ------
  if (!ATOMIC) {
    // bf16-packed: u32 slot s in [0,32) holds cols (s, s+32) as (lo16, hi16)
    unsigned int* P = (unsigned int*)Iout;
    #pragma unroll
    for (int j = 0; j < 4; ++j) {
      const int row = wv * 16 + lg * 4 + j;
      const size_t base = ((size_t)(b * NW + w) * NQ + row) * 32;
      P[base + l16]      = cvtpk(acc[0][j], acc[2][j]);
      P[base + l16 + 16] = cvtpk(acc[1][j], acc[3][j]);
    }
  } else {
    float* Iacc = (float*)Iout;
    #pragma unroll
    for (int cf = 0; cf < 4; ++cf)
      #pragma unroll
      for (int j = 0; j < 4; ++j) {
        const int row = wv * 16 + lg * 4 + j;
        atomicAdd(&Iacc[((size_t)b * NQ + row) * KT + cf * 16 + l16], acc[cf][j]);
      }
  }

  // ---- A rowsums: reduce the 4 lanes (lg) sharing each row -----------------
  rsA += __shfl_xor(rsA, 16); rsA += __shfl_xor(rsA, 32);
  if (lg == 0) {
    const int row = wv * 16 + l16;
    if (!ATOMIC) RSin[(size_t)(b * NW + w) * NQ + row] = rsA;
    else         atomicAdd(&RSin[b * NQ + row], rsA);
  }
}

// ---------------- stage 2 (partial mode): reduce + dice + class gather ------
__global__ __launch_bounds__(256)
void hm_stage2(const float* __restrict__ cprob, const void* __restrict__ tcls,
               const unsigned int* __restrict__ P, const float* __restrict__ RSin,
               const float* __restrict__ RStg, float* __restrict__ out) {
  const int bn = blockIdx.x;            // b*NQ + n
  const int b = bn >> 7, n = bn & 127;
  const int k = threadIdx.x & 63;
  const int wq = threadIdx.x >> 6;      // 0..3
  const int slot = k & 31;
  const bool hi = k >= 32;
  float I = 0.f, ra = 0.f, rg = 0.f;
  #pragma unroll 8
  for (int ww = 0; ww < NW / 4; ++ww) {
    const int w = wq * (NW / 4) + ww;
    const unsigned int v = P[((size_t)(b * NW + w) * NQ + n) * 32 + slot];
    const unsigned int bits = hi ? (v & 0xffff0000u) : (v << 16);
    I  += __uint_as_float(bits);
    ra += RSin[(size_t)(b * NW + w) * NQ + n];
    rg += RStg[(size_t)(b * NW + w) * KT + k];
  }
  __shared__ float sI[4][64];
  __shared__ float sG[4][64];
  __shared__ float sR[4];
  sI[wq][k] = I;
  sG[wq][k] = rg;
  if (k == 0) sR[wq] = ra;
  __syncthreads();
  if (wq == 0) {
    I  = sI[0][k] + sI[1][k] + sI[2][k] + sI[3][k];
    rg = sG[0][k] + sG[1][k] + sG[2][k] + sG[3][k];
    ra = sR[0] + sR[1] + sR[2] + sR[3];
    const unsigned int hiw = ((const unsigned int*)tcls)[k * 2 + 1];
    const bool i32 = (__ballot(hiw != 0u) != 0ull);
    int tc = i32 ? ((const int*)tcls)[b * KT + k]
                 : (int)((const long long*)tcls)[b * KT + k];
    const float c = cprob[((size_t)b * NQ + n) * CC + tc];
    out[(size_t)bn * KT + k] = c * (2.f * I + EPSI) / (ra + rg + EPSI);
  }
}

// ---------------- stage 2 (atomic fallback mode) ----------------------------
__global__ __launch_bounds__(256)
void hm_stage2_direct(const float* __restrict__ cprob, const void* __restrict__ tcls,
                      const unsigned int* __restrict__ flag,
                      const float* __restrict__ Iacc, const float* __restrict__ RSin,
                      const float* __restrict__ RStg, float* __restrict__ out) {
  const int idx = blockIdx.x * 256 + threadIdx.x;
  const int k = idx & 63;
  const int n = (idx >> 6) & 127;
  const int b = idx >> 13;
  const float I  = Iacc[idx];
  const float ra = RSin[b * NQ + n];
  const float rg = RStg[b * KT + k];
  int tc;
  if (*flag) tc = ((const int*)tcls)[b * KT + k];
  else       tc = (int)((const long long*)tcls)[b * KT + k];
  const float c = cprob[((size_t)b * NQ + n) * CC + tc];
  out[idx] = c * (2.f * I + EPSI) / (ra + rg + EPSI);
}

__global__ void hm_zero(float* __restrict__ p, int n) {
  int i = blockIdx.x * blockDim.x + threadIdx.x;
  if (i < n) p[i] = 0.f;
}

extern "C" void kernel_launch(void* const* d_in, const int* in_sizes, int n_in,
                              void* d_out, int out_size, void* d_ws, size_t ws_size,
                              hipStream_t stream) {
  const float* cprob = (const float*)d_in[0];   // (2,128,134) f32
  const float* imask = (const float*)d_in[1];   // (2,128,65536) f32
  const float* tmask = (const float*)d_in[2];   // (2,64,65536) f32
  const void*  tcls  = d_in[3];                 // (2,64) int64 (or int32)
  float* out = (float*)d_out;                   // (2,128,64) f32

  const size_t p_u32  = (size_t)BB * NW * NQ * 32;   // 1 Mi u32 (4 MB, bf16 pairs)
  const size_t rsin_f = (size_t)BB * NW * NQ;        // 32,768
  const size_t rstg_f = (size_t)BB * NW * KT;        // 16,384
  const size_t need   = (p_u32 + rsin_f + rstg_f) * 4;

  char* ws = (char*)d_ws;
  if (ws_size >= need) {
    unsigned int* P = (unsigned int*)ws;
    float* RSin = (float*)(P + p_u32);
    float* RStg = RSin + rsin_f;
    hm_stage1<false><<<BB * NW, 512, 0, stream>>>(imask, tmask, P, RSin, RStg);
    hm_stage2<<<BB * NQ, 256, 0, stream>>>(cprob, tcls, P, RSin, RStg, out);
  } else {
    // small-scratch atomic fallback (~67 KB)
    float* Iacc = (float*)ws;                     // 16384 floats
    float* RSin = Iacc + (size_t)BB * NQ * KT;    // 256
    float* RStg = RSin + BB * NQ;                 // 128
    unsigned int* flag = (unsigned int*)(RStg + BB * KT);
    const int zn = BB * NQ * KT + BB * NQ + BB * KT;
    hm_zero<<<(zn + 255) / 256, 256, 0, stream>>>(Iacc, zn);
    hm_detect<<<1, 64, 0, stream>>>((const unsigned int*)tcls, flag);
    hm_stage1<true><<<BB * NW, 512, 0, stream>>>(imask, tmask, Iacc, RSin, RStg);
    hm_stage2_direct<<<(BB * NQ * KT) / 256, 256, 0, stream>>>(cprob, tcls, flag, Iacc, RSin, RStg, out);
  }
}